// Round 9
// baseline (38.703 us; speedup 1.0000x reference)
//
#include <hip/hip_runtime.h>

#define NFILT 80
#define NBINS 257            // 512/2+1
#define NPTS  82             // binpoints
#define ROWS  64             // rows per tile (= lanes)
#define BLOCK 512            // 8 waves
#define NW    8
#define GRID  512            // 2 blocks per CU
#define OPAD  81             // sout row stride: bank=(17*lane+f)%32, conflict-free
#define CHUNKS 4112          // 64*257/4 float4 chunks per tile
#define CHUNKS_PAD 4160      // pad for wave0's clamped extra DMA instrs
#define TFLOAT (ROWS * NBINS)
#define FPW   10             // filters per wave (wave w owns [10w, 10w+10))
#define SPT   ((ROWS * NFILT) / BLOCK)   // store elems per thread = 10

// Async DMA one tile (66KB) global->LDS. 8 instrs/thread + 1 extra for wave0.
// LDS dest linear in lane order (wave-uniform base + lane*16) as required.
__device__ __forceinline__ void stage(const float* __restrict__ x, int tg,
                                      float* ldst, int tid, int wv, int lane) {
    const float* gsrc = x + (size_t)tg * TFLOAT;
#pragma unroll
    for (int j = 0; j < 8; ++j) {                  // chunks 0..4095
        int ci = tid + j * BLOCK;
        __builtin_amdgcn_global_load_lds(
            (const __attribute__((address_space(1))) void*)(gsrc + ci * 4),
            (__attribute__((address_space(3))) void*)(ldst + ci * 4), 16, 0, 0);
    }
    if (wv == 0) {                                 // chunks 4096..4111 (+pad)
        int ci = 4096 + lane;
        int cs = ci <= 4111 ? ci : 4111;           // clamp src; excess -> pad
        __builtin_amdgcn_global_load_lds(
            (const __attribute__((address_space(1))) void*)(gsrc + cs * 4),
            (__attribute__((address_space(3))) void*)(ldst + ci * 4), 16, 0, 0);
    }
}

// Streaming per-bin weights: bin k in segment s contributes wr[k] to filter s
// (rise) and wf[k] to filter s-1 (fall). Wave w sweeps segments 10w..10w+10
// (1-seg overlap, no handoff), outputs in registers, staged through the dead
// x-tile head for coalesced stores. Key pipeline trick: next-tile DMA is
// issued BEFORE the stores, so s_waitcnt vmcnt(10) retires exactly the DMA
// (oldest 8|9 ops) and leaves all 10 stores in flight across the barrier --
// store drain overlaps the next compute phase. 2 independent blocks/CU
// provide stage/compute overlap.
__global__ __launch_bounds__(BLOCK, 4) void filter_kernel(
        const float* __restrict__ x, const float* __restrict__ bp,
        float* __restrict__ out, int tiles) {
    __shared__ __align__(16) float sx[CHUNKS_PAD * 4];     // 66560 B
    __shared__ __align__(8)  float sw[2 * NBINS];          // 2056 B
    __shared__ float sb[NPTS];                             // 328 B
    __shared__ int   sli[NPTS];                            // 328 B floor(b[s])
    __shared__ int   sflag;
    // total ~69.3 KB -> 2 blocks/CU, 16 waves/CU

    const int tid  = threadIdx.x;
    const int lane = tid & 63;
    const int wv   = __builtin_amdgcn_readfirstlane(tid >> 6);

    const int bid  = blockIdx.x;
    const int base = tiles / GRID, rem = tiles % GRID;
    const int t0   = bid * base + min(bid, rem);
    const int cnt  = base + (bid < rem ? 1 : 0);
    if (cnt <= 0) return;

    // ---- prologue: T0 DMA first, table prep under its latency ----
    stage(x, t0, sx, tid, wv, lane);
    if (tid == 0) sflag = 0;
    if (tid < NPTS) sb[tid] = bp[tid];
    for (int i = tid; i < 2 * NBINS; i += BLOCK) sw[i] = 0.f;
    __syncthreads();
    if (tid < NPTS - 1 && sb[tid] > sb[tid + 1]) sflag = 1;
    __syncthreads();
    if (sflag) {                           // input unsorted (not expected)
        if (tid == 0) {
            for (int i = 1; i < NPTS; ++i) {
                float v = sb[i]; int j = i - 1;
                while (j >= 0 && sb[j] > v) { sb[j + 1] = sb[j]; --j; }
                sb[j + 1] = v;
            }
        }
        __syncthreads();
    }
    if (tid <= 80) sli[tid] = (int)floorf(sb[tid]);
    if (tid == 81) sli[81] = (int)floorf(sb[80]);   // sentinel
    __syncthreads();
    if (tid < 80) {                        // thread s fills its segment's bins
        int s  = tid;
        int k0 = sli[s], k1 = sli[s + 1];
        float bs = sb[s], bs1 = sb[s + 1];
        float d = bs1 - bs, D = d * d;
        float invD = (D == 0.f) ? 1.f : 1.f / D;
        for (int k = k0; k < k1; ++k) {
            sw[2 * k]     = (s <= 78) ? ((float)k - bs) * invD : 0.f;  // rise(s)
            sw[2 * k + 1] = (s >= 1)  ? (bs1 - (float)k) * invD : 0.f; // fall(s-1)
        }
    }
    asm volatile("s_waitcnt vmcnt(0)" ::: "memory");   // T0 + bp landed
    __syncthreads();                                   // tables visible

    const float2* swp = (const float2*)sw;
    const int fa = FPW * wv;               // wave owns filters [fa, fa+10)

    for (int tl = 0; tl < cnt; ++tl) {
        // head invariant: sx holds tile tl, landed for all waves
        const float* xr = &sx[lane * NBINS];

        // ---- compute: sweep 11 segments, 10 outputs in registers ----
        float res[FPW];
        float xv0 = xr[0];                 // for wave0's filter-0 overwrite
        int k = __builtin_amdgcn_readfirstlane(sli[fa]);
        float r_prev = 0.f;
#pragma unroll
        for (int e = 0; e <= FPW; ++e) {   // full unroll -> static res indices
            const int s  = fa + e;
            const int k1 = __builtin_amdgcn_readfirstlane(sli[s + 1]);
            float racc = 0.f, facc = 0.f;
            if (k < k1) {                  // load-ahead software pipeline
                float  xv = xr[k];
                float2 w2 = swp[k];
                for (; k + 1 < k1; ++k) {
                    float  xn = xr[k + 1];          // in flight during FMAs
                    float2 wn = swp[k + 1];
                    racc = fmaf(xv, w2.x, racc);
                    facc = fmaf(xv, w2.y, facc);
                    xv = xn; w2 = wn;
                }
                racc = fmaf(xv, w2.x, racc);
                facc = fmaf(xv, w2.y, facc);
                ++k;
            }
            if (e > 0) res[e - 1] = r_prev + facc;  // filter fa+e-1
            r_prev = racc;
        }
        if (wv == 0)      res[0] = xv0;    // filtered[:,:,0] = x[:,:,0]
        if (wv == NW - 1) res[FPW - 1] = 0.f;  // fbank row 79 is zeros

        asm volatile("s_waitcnt lgkmcnt(0)" ::: "memory");
        __builtin_amdgcn_s_barrier();      // B1: all x-reads of sx done -> dead
        __builtin_amdgcn_sched_barrier(0);

        // ---- transpose through LDS: res -> sx head as [ROWS][OPAD] ----
        float* so = sx + lane * OPAD;
#pragma unroll
        for (int e = 0; e < FPW; ++e) so[fa + e] = res[e];
        asm volatile("s_waitcnt lgkmcnt(0)" ::: "memory");
        __builtin_amdgcn_s_barrier();      // B2: sout visible to all waves
        __builtin_amdgcn_sched_barrier(0);

        // ---- pull coalesced store data into VGPRs ----
        float vout[SPT];
#pragma unroll
        for (int j = 0; j < SPT; ++j) {
            int i = tid + j * BLOCK;
            int r = i / NFILT;
            vout[j] = sx[r * OPAD + (i - r * NFILT)];
        }
        float* ob = out + (size_t)(t0 + tl) * (ROWS * NFILT);

        if (tl == cnt - 1) {               // last tile: just store and exit
#pragma unroll
            for (int j = 0; j < SPT; ++j) ob[tid + j * BLOCK] = vout[j];
            break;
        }

        asm volatile("s_waitcnt lgkmcnt(0)" ::: "memory");
        __builtin_amdgcn_s_barrier();      // B3: all ds_reads done -> sx free
        __builtin_amdgcn_sched_barrier(0);

        // ---- issue next DMA FIRST (oldest), then stores (newest) ----
        stage(x, t0 + tl + 1, sx, tid, wv, lane);
        __builtin_amdgcn_sched_barrier(0);
#pragma unroll
        for (int j = 0; j < SPT; ++j) ob[tid + j * BLOCK] = vout[j];
        __builtin_amdgcn_sched_barrier(0);
        // outstanding: DMA 8|9 (oldest) + 10 stores (newest). Retire exactly
        // the DMA; leave stores in flight across the barrier:
        asm volatile("s_waitcnt vmcnt(10)" ::: "memory");
        __builtin_amdgcn_s_barrier();      // B4: tile tl+1 landed for ALL waves
        __builtin_amdgcn_sched_barrier(0);
    }
}

extern "C" void kernel_launch(void* const* d_in, const int* in_sizes, int n_in,
                              void* d_out, int out_size, void* d_ws, size_t ws_size,
                              hipStream_t stream) {
    const float* x  = (const float*)d_in[0];
    const float* bp = (const float*)d_in[1];
    float* out = (float*)d_out;

    const int nrows = in_sizes[0] / NBINS;   // 131072
    const int tiles = nrows / ROWS;          // 2048

    filter_kernel<<<GRID, BLOCK, 0, stream>>>(x, bp, out, tiles);
}